// Round 17
// baseline (1364.702 us; speedup 1.0000x reference)
//
#include <hip/hip_runtime.h>
#include <hip/hip_bf16.h>
#include <cmath>

#define D_MODEL 128
#define NUM_HEAD 4
#define HEAD_DIM 32
#define SEQ 4096
#define BATCH 2
#define QTILE 64   // q-rows per tile
#define NWB 16     // waves per attention block
#define CHUNK 8    // k-rows per staged chunk
#define RROWS 8    // token rows per projection block

__device__ __forceinline__ float tof(float x) { return x; }
__device__ __forceinline__ float tof(__hip_bfloat16 x) { return __bfloat162float(x); }
__device__ __forceinline__ void storef(float* p, size_t i, float v) { p[i] = v; }
__device__ __forceinline__ void storef(__hip_bfloat16* p, size_t i, float v) { p[i] = __float2bfloat16(v); }
__device__ __forceinline__ float4 load4(const float* p) { return *(const float4*)p; }
__device__ __forceinline__ float4 load4(const __hip_bfloat16* p) {
    return make_float4(tof(p[0]), tof(p[1]), tof(p[2]), tof(p[3]));
}

// ---------------------------------------------------------------------------
// Kernel 0: dtype detector (f32 vs bf16 inputs), unchanged (passes since R3).
// ---------------------------------------------------------------------------
__global__ void detect_kernel(const unsigned short* __restrict__ w, int* __restrict__ flag)
{
    const int t = threadIdx.x;   // 64 threads
    int weird = 0;
#pragma unroll
    for (int j = 0; j < 4; ++j) {
        const unsigned short v = w[(t * 4 + j) * 2 + 1];
        const float x = __uint_as_float((unsigned)v << 16);
        const float a = fabsf(x);
        if (a > 1e20f || (a > 0.f && a < 1e-20f)) weird++;
    }
#pragma unroll
    for (int off = 32; off; off >>= 1) weird += __shfl_xor(weird, off);
    if (t == 0) *flag = (weird < 32) ? 1 : 0;
}

// ---------------------------------------------------------------------------
// Kernel 1: x = embedding[seq] + PE;  Q/K/V = x @ W^T  (f32 to workspace)
// ---------------------------------------------------------------------------
template <typename T>
__device__ __forceinline__ void qkv_body(
    const int* __restrict__ seq, const T* __restrict__ emb,
    const T* __restrict__ wq, const T* __restrict__ wk, const T* __restrict__ wv,
    float* __restrict__ Q, float* __restrict__ K, float* __restrict__ V)
{
    const int e = threadIdx.x;               // 0..127 output dim
    const int r0 = blockIdx.x * RROWS;
    __shared__ __align__(16) float xs[RROWS][D_MODEL];

    {
        const int i = e >> 1;
        const double inv = 1.0 / pow(10000.0, (double)i / 64.0);
        const int s0 = r0 & (SEQ - 1);
        double c = cos((double)s0 * inv);
        double s = sin((double)s0 * inv);
        const double cd = cos(inv), sd = sin(inv);
        const bool odd = (e & 1);
#pragma unroll
        for (int r = 0; r < RROWS; ++r) {
            const float pe = (float)(odd ? c : s);
            xs[r][e] = tof(emb[(size_t)seq[r0 + r] * D_MODEL + e]) + pe;
            const double cn = c * cd - s * sd;
            s = s * cd + c * sd;
            c = cn;
        }
    }
    __syncthreads();

    const T* wqr = wq + e * D_MODEL;
    const T* wkr = wk + e * D_MODEL;
    const T* wvr = wv + e * D_MODEL;
    float aq[RROWS], ak[RROWS], av[RROWS];
#pragma unroll
    for (int r = 0; r < RROWS; ++r) { aq[r] = 0.f; ak[r] = 0.f; av[r] = 0.f; }

    for (int c = 0; c < 32; ++c) {
        const float4 wq4 = load4(wqr + 4 * c);
        const float4 wk4 = load4(wkr + 4 * c);
        const float4 wv4 = load4(wvr + 4 * c);
#pragma unroll
        for (int r = 0; r < RROWS; ++r) {
            const float4 x4 = *(const float4*)&xs[r][4*c];
            aq[r] += x4.x*wq4.x + x4.y*wq4.y + x4.z*wq4.z + x4.w*wq4.w;
            ak[r] += x4.x*wk4.x + x4.y*wk4.y + x4.z*wk4.z + x4.w*wk4.w;
            av[r] += x4.x*wv4.x + x4.y*wv4.y + x4.z*wv4.z + x4.w*wv4.w;
        }
    }
#pragma unroll
    for (int r = 0; r < RROWS; ++r) {
        const size_t o = (size_t)(r0 + r) * D_MODEL + e;
        Q[o] = aq[r]; K[o] = ak[r]; V[o] = av[r];
    }
}

__global__ __launch_bounds__(128) void qkv_kernel(
    const int* __restrict__ seq, const void* emb,
    const void* wq, const void* wk, const void* wv,
    float* __restrict__ Q, float* __restrict__ K, float* __restrict__ V,
    const int* __restrict__ flag)
{
    if (*flag)
        qkv_body<float>(seq, (const float*)emb, (const float*)wq,
                        (const float*)wk, (const float*)wv, Q, K, V);
    else
        qkv_body<__hip_bfloat16>(seq, (const __hip_bfloat16*)emb, (const __hip_bfloat16*)wq,
                                 (const __hip_bfloat16*)wk, (const __hip_bfloat16*)wv, Q, K, V);
}

// ---------------------------------------------------------------------------
// Kernel 2 (R17): 16-wave single block per CU. 256 blocks x 1024 threads ->
// guaranteed 4 waves/SIMD (the grid-level 2-blocks/CU attempts R13/R16 both
// failed on placement). The (big,small)=(63-pair,pair) tile pair's 520
// chunks are split contiguously: waves 0..g-1 take tile0, g..15 tile1, each
// wave ~32-35 chunks -> per-SIMD load within ~6% of the 130-chunk ideal.
// Body = R15's proven pair-split (half-D per lane, 2 rows/lane, DPP xor-1
// combine, per-wave LDS staging w/ register prefetch, ~120 VGPR).
// launch_bounds(1024,1): fitted cap formula min(128, 512/(2*arg)) -> 128.
// Combine: 16 sub-passes of 4 dims (part 24KB; +stage 32KB = 57.3KB LDS);
// non-contributing waves write identity partials (m=0,l=0,o=0 - neutral).
// ---------------------------------------------------------------------------
__global__ __launch_bounds__(1024, 1) void attn_kernel(
    const float* __restrict__ Q, const float* __restrict__ K,
    const float* __restrict__ V, float* __restrict__ O)
{
    const int bh   = blockIdx.x;            // fast axis -> XCD = bh
    const int pair = blockIdx.y;            // 0..31
    const int qt0 = 63 - pair, qt1 = pair;
    const int C0 = 8 * (qt0 + 1);           // chunks in tile0
    const int C1 = 8 * (qt1 + 1);           // C0 + C1 = 520
    const size_t base = (size_t)(bh >> 2) * SEQ * D_MODEL + (size_t)(bh & 3) * SEQ * HEAD_DIM;
    const float* Qh = Q + base;
    const float* Kh = K + base;
    const float* Vh = V + base;
    float*       Oh = O + base;

    const int tid  = threadIdx.x;
    const int wid  = __builtin_amdgcn_readfirstlane(tid >> 6);  // 0..15
    const int lane = tid & 63;
    const int half = lane & 1;              // 0: dims 0..15, 1: dims 16..31
    const int pr   = lane >> 1;             // 0..31

    // wave -> tile + chunk-range assignment (all wave-uniform)
    int g = (16 * C0 + 260) / 520;          // round(16*C0/520)
    g = (g < 1) ? 1 : ((g > 15) ? 15 : g);
    const int tile = (wid < g) ? 1 : 2;     // 1 = tile0, 2 = tile1 (avoid 0 for clarity)
    const int Gs   = (tile == 1) ? g : (16 - g);
    const int idx  = (tile == 1) ? wid : (wid - g);
    const int n    = (tile == 1) ? C0 : C1;
    const int nb   = n / Gs, rem = n % Gs;
    const int cnt  = nb + ((idx < rem) ? 1 : 0);
    const int cbeg = idx * nb + ((idx < rem) ? idx : rem);
    const int qt   = (tile == 1) ? qt0 : qt1;
    const int rowA = qt * QTILE + pr;
    const int rowB = rowA + 32;

    __shared__ __align__(16) float stage[NWB][2 * CHUNK * HEAD_DIM];  // 32 KB
    __shared__ float part[NWB][QTILE][6];                             // 24 KB

    const float scale = 0.17677669529663687f;   // 1/sqrt(32), folded into q
    float qv0[16], qv1[16];
#pragma unroll
    for (int j4 = 0; j4 < 4; ++j4) {
        const float4 a = *(const float4*)(Qh + (size_t)rowA * HEAD_DIM + half * 16 + 4 * j4);
        const float4 b = *(const float4*)(Qh + (size_t)rowB * HEAD_DIM + half * 16 + 4 * j4);
        qv0[4*j4] = a.x*scale; qv0[4*j4+1] = a.y*scale; qv0[4*j4+2] = a.z*scale; qv0[4*j4+3] = a.w*scale;
        qv1[4*j4] = b.x*scale; qv1[4*j4+1] = b.y*scale; qv1[4*j4+2] = b.z*scale; qv1[4*j4+3] = b.w*scale;
    }

    float ov0[16], ov1[16];
#pragma unroll
    for (int j = 0; j < 16; ++j) { ov0[j] = 0.f; ov1[j] = 0.f; }
    float m0 = 0.f, l0 = 0.f, m1 = 0.f, l1 = 0.f;

    // staging roles: lanes 0..31 -> K, lanes 32..63 -> V; 32B each
    const int sl = lane & 31;
    const float* gsrc0 = (lane < 32) ? Kh : Vh;
    float* dst = &stage[wid][((lane >= 32) ? CHUNK * HEAD_DIM : 0) + sl * 8];

    float4 pa, pb;
    {
        const float* src = gsrc0 + (size_t)cbeg * CHUNK * HEAD_DIM + sl * 8;
        pa = *(const float4*)(src);
        pb = *(const float4*)(src + 4);
    }

    for (int c = cbeg; c < cbeg + cnt; ++c) {
        *(float4*)(dst)     = pa;
        *(float4*)(dst + 4) = pb;
        if (c + 1 < cbeg + cnt) {
            const float* src = gsrc0 + (size_t)(c + 1) * CHUNK * HEAD_DIM + sl * 8;
            pa = *(const float4*)(src);
            pb = *(const float4*)(src + 4);
        }
        const int k0 = c * CHUNK;

        // ---- QK: each lane half-dots both rows, combine via DPP xor-1 ----
        float p0[CHUNK], p1[CHUNK];
        float cm0 = m0, cm1 = m1;
#pragma unroll
        for (int i = 0; i < CHUNK; ++i) {
            const float* kr = &stage[wid][i * HEAD_DIM + half * 16];
            float s0 = 0.f, s1 = 0.f;
#pragma unroll
            for (int j4 = 0; j4 < 4; ++j4) {
                const float4 kk = *(const float4*)(kr + 4 * j4);
                s0 += qv0[4*j4]*kk.x + qv0[4*j4+1]*kk.y + qv0[4*j4+2]*kk.z + qv0[4*j4+3]*kk.w;
                s1 += qv1[4*j4]*kk.x + qv1[4*j4+1]*kk.y + qv1[4*j4+2]*kk.z + qv1[4*j4+3]*kk.w;
            }
            s0 += __shfl_xor(s0, 1, 64);    // partner half (DPP, VALU pipe)
            s1 += __shfl_xor(s1, 1, 64);
            const int k = k0 + i;
            p0[i] = (k <= rowA) ? fabsf(s0) : -1.f;
            p1[i] = (k <= rowB) ? fabsf(s1) : -1.f;
            cm0 = fmaxf(cm0, p0[i]);
            cm1 = fmaxf(cm1, p1[i]);
        }
        const float a0 = __expf(m0 - cm0);
        const float a1 = __expf(m1 - cm1);
        l0 *= a0; m0 = cm0; l1 *= a1; m1 = cm1;
#pragma unroll
        for (int j = 0; j < 16; ++j) { ov0[j] *= a0; ov1[j] *= a1; }

        // ---- PV: each lane accumulates its 16-dim half for both rows ----
#pragma unroll
        for (int i = 0; i < CHUNK; ++i) {
            const float e0 = (p0[i] >= 0.f) ? __expf(p0[i] - m0) : 0.f;
            const float e1 = (p1[i] >= 0.f) ? __expf(p1[i] - m1) : 0.f;
            l0 += e0; l1 += e1;
            const float* vr = &stage[wid][CHUNK * HEAD_DIM + i * HEAD_DIM + half * 16];
#pragma unroll
            for (int j4 = 0; j4 < 4; ++j4) {
                const float4 vv = *(const float4*)(vr + 4 * j4);
                ov0[4*j4]   += e0 * vv.x; ov0[4*j4+1] += e0 * vv.y;
                ov0[4*j4+2] += e0 * vv.z; ov0[4*j4+3] += e0 * vv.w;
                ov1[4*j4]   += e1 * vv.x; ov1[4*j4+1] += e1 * vv.y;
                ov1[4*j4+2] += e1 * vv.z; ov1[4*j4+3] += e1 * vv.w;
            }
        }
    }

    // ---- combine: 2 tiles x 2 halves x 4 sub-passes of 4 dims ----
    for (int t = 1; t <= 2; ++t) {
        const int qtt = (t == 1) ? qt0 : qt1;
        for (int h = 0; h < 2; ++h) {
            for (int s = 0; s < 4; ++s) {
                __syncthreads();
                if (half == h) {
                    if (tile == t) {
#pragma unroll
                        for (int d = 0; d < 4; ++d) {
                            part[wid][pr][d]      = ov0[s * 4 + d];
                            part[wid][pr + 32][d] = ov1[s * 4 + d];
                        }
                        part[wid][pr][4]      = m0; part[wid][pr][5]      = l0;
                        part[wid][pr + 32][4] = m1; part[wid][pr + 32][5] = l1;
                    } else {
#pragma unroll
                        for (int d = 0; d < 6; ++d) {
                            part[wid][pr][d]      = 0.f;
                            part[wid][pr + 32][d] = 0.f;
                        }
                    }
                }
                __syncthreads();
                if (tid < 256) {
                    const int r = tid >> 2, d = tid & 3;
                    float M = 0.f;
#pragma unroll
                    for (int w = 0; w < NWB; ++w) M = fmaxf(M, part[w][r][4]);
                    float lsum = 0.f, osum = 0.f;
#pragma unroll
                    for (int w = 0; w < NWB; ++w) {
                        const float a = __expf(part[w][r][4] - M);
                        lsum += a * part[w][r][5];
                        osum += a * part[w][r][d];
                    }
                    Oh[(size_t)(qtt * QTILE + r) * HEAD_DIM + h * 16 + s * 4 + d] = osum / lsum;
                }
            }
        }
    }
}

// ---------------------------------------------------------------------------
// Kernel 3: out = att @ Wo^T  (RROWS=8, float4 weight loads)
// ---------------------------------------------------------------------------
template <typename T>
__device__ __forceinline__ void out_proj_body(
    const float* __restrict__ att, const T* __restrict__ wo, T* __restrict__ out)
{
    const int e = threadIdx.x;
    const int r0 = blockIdx.x * RROWS;
    __shared__ __align__(16) float xs[RROWS][D_MODEL];
#pragma unroll
    for (int r = 0; r < RROWS; ++r)
        xs[r][e] = att[(size_t)(r0 + r) * D_MODEL + e];
    __syncthreads();

    const T* wr = wo + e * D_MODEL;
    float acc[RROWS];
#pragma unroll
    for (int r = 0; r < RROWS; ++r) acc[r] = 0.f;
    for (int c = 0; c < 32; ++c) {
        const float4 w4 = load4(wr + 4 * c);
#pragma unroll
        for (int r = 0; r < RROWS; ++r) {
            const float4 x4 = *(const float4*)&xs[r][4*c];
            acc[r] += x4.x*w4.x + x4.y*w4.y + x4.z*w4.z + x4.w*w4.w;
        }
    }
#pragma unroll
    for (int r = 0; r < RROWS; ++r)
        storef(out, (size_t)(r0 + r) * D_MODEL + e, acc[r]);
}

__global__ __launch_bounds__(128) void out_proj_kernel(
    const float* __restrict__ att, const void* wo, void* out,
    const int* __restrict__ flag)
{
    if (*flag)
        out_proj_body<float>(att, (const float*)wo, (float*)out);
    else
        out_proj_body<__hip_bfloat16>(att, (const __hip_bfloat16*)wo, (__hip_bfloat16*)out);
}

extern "C" void kernel_launch(void* const* d_in, const int* in_sizes, int n_in,
                              void* d_out, int out_size, void* d_ws, size_t ws_size,
                              hipStream_t stream) {
    const int* seq = (const int*)d_in[0];
    const void* emb = d_in[1];
    const void* wq  = d_in[2];
    const void* wk  = d_in[3];
    const void* wv  = d_in[4];
    const void* wo  = d_in[5];

    const size_t N = (size_t)BATCH * SEQ * D_MODEL;   // 1,048,576
    int*   flag = (int*)d_ws;
    float* Q = (float*)((char*)d_ws + 256);
    float* K = Q + N;
    float* V = K + N;
    float* A = Q;   // alias: each attn block reads only its own Q rows first

    detect_kernel<<<dim3(1), dim3(64), 0, stream>>>((const unsigned short*)wq, flag);
    qkv_kernel<<<dim3(BATCH * SEQ / RROWS), dim3(128), 0, stream>>>(seq, emb, wq, wk, wv, Q, K, V, flag);
    attn_kernel<<<dim3(BATCH * NUM_HEAD, SEQ / QTILE / 2), dim3(1024), 0, stream>>>(Q, K, V, A);
    out_proj_kernel<<<dim3(BATCH * SEQ / RROWS), dim3(128), 0, stream>>>(A, wo, d_out, flag);
}

// Round 18
// 331.520 us; speedup vs baseline: 4.1165x; 4.1165x over previous
//
#include <hip/hip_runtime.h>
#include <hip/hip_bf16.h>
#include <cmath>

#define D_MODEL 128
#define NUM_HEAD 4
#define HEAD_DIM 32
#define SEQ 4096
#define BATCH 2
#define QTILE 64   // q-rows per tile
#define NW 8       // waves per attention block (k-split factor)
#define CHUNK 8    // k-rows per staged chunk
#define RROWS 8    // token rows per projection block
#define PSTRIDE 36 // floats per row partial: o[32], m, l, pad

__device__ __forceinline__ float tof(float x) { return x; }
__device__ __forceinline__ float tof(__hip_bfloat16 x) { return __bfloat162float(x); }
__device__ __forceinline__ void storef(float* p, size_t i, float v) { p[i] = v; }
__device__ __forceinline__ void storef(__hip_bfloat16* p, size_t i, float v) { p[i] = __float2bfloat16(v); }
__device__ __forceinline__ float4 load4(const float* p) { return *(const float4*)p; }
__device__ __forceinline__ float4 load4(const __hip_bfloat16* p) {
    return make_float4(tof(p[0]), tof(p[1]), tof(p[2]), tof(p[3]));
}

// ---------------------------------------------------------------------------
// Kernel 0: dtype detector (f32 vs bf16 inputs), unchanged (passes since R3).
// ---------------------------------------------------------------------------
__global__ void detect_kernel(const unsigned short* __restrict__ w, int* __restrict__ flag)
{
    const int t = threadIdx.x;   // 64 threads
    int weird = 0;
#pragma unroll
    for (int j = 0; j < 4; ++j) {
        const unsigned short v = w[(t * 4 + j) * 2 + 1];
        const float x = __uint_as_float((unsigned)v << 16);
        const float a = fabsf(x);
        if (a > 1e20f || (a > 0.f && a < 1e-20f)) weird++;
    }
#pragma unroll
    for (int off = 32; off; off >>= 1) weird += __shfl_xor(weird, off);
    if (t == 0) *flag = (weird < 32) ? 1 : 0;
}

// ---------------------------------------------------------------------------
// Kernel 1: x = embedding[seq] + PE;  Q/K/V = x @ W^T  (f32 to workspace)
// ---------------------------------------------------------------------------
template <typename T>
__device__ __forceinline__ void qkv_body(
    const int* __restrict__ seq, const T* __restrict__ emb,
    const T* __restrict__ wq, const T* __restrict__ wk, const T* __restrict__ wv,
    float* __restrict__ Q, float* __restrict__ K, float* __restrict__ V)
{
    const int e = threadIdx.x;               // 0..127 output dim
    const int r0 = blockIdx.x * RROWS;
    __shared__ __align__(16) float xs[RROWS][D_MODEL];

    {
        const int i = e >> 1;
        const double inv = 1.0 / pow(10000.0, (double)i / 64.0);
        const int s0 = r0 & (SEQ - 1);
        double c = cos((double)s0 * inv);
        double s = sin((double)s0 * inv);
        const double cd = cos(inv), sd = sin(inv);
        const bool odd = (e & 1);
#pragma unroll
        for (int r = 0; r < RROWS; ++r) {
            const float pe = (float)(odd ? c : s);
            xs[r][e] = tof(emb[(size_t)seq[r0 + r] * D_MODEL + e]) + pe;
            const double cn = c * cd - s * sd;
            s = s * cd + c * sd;
            c = cn;
        }
    }
    __syncthreads();

    const T* wqr = wq + e * D_MODEL;
    const T* wkr = wk + e * D_MODEL;
    const T* wvr = wv + e * D_MODEL;
    float aq[RROWS], ak[RROWS], av[RROWS];
#pragma unroll
    for (int r = 0; r < RROWS; ++r) { aq[r] = 0.f; ak[r] = 0.f; av[r] = 0.f; }

    for (int c = 0; c < 32; ++c) {
        const float4 wq4 = load4(wqr + 4 * c);
        const float4 wk4 = load4(wkr + 4 * c);
        const float4 wv4 = load4(wvr + 4 * c);
#pragma unroll
        for (int r = 0; r < RROWS; ++r) {
            const float4 x4 = *(const float4*)&xs[r][4*c];
            aq[r] += x4.x*wq4.x + x4.y*wq4.y + x4.z*wq4.z + x4.w*wq4.w;
            ak[r] += x4.x*wk4.x + x4.y*wk4.y + x4.z*wk4.z + x4.w*wk4.w;
            av[r] += x4.x*wv4.x + x4.y*wv4.y + x4.z*wv4.z + x4.w*wv4.w;
        }
    }
#pragma unroll
    for (int r = 0; r < RROWS; ++r) {
        const size_t o = (size_t)(r0 + r) * D_MODEL + e;
        Q[o] = aq[r]; K[o] = ak[r]; V[o] = av[r];
    }
}

__global__ __launch_bounds__(128) void qkv_kernel(
    const int* __restrict__ seq, const void* emb,
    const void* wq, const void* wk, const void* wv,
    float* __restrict__ Q, float* __restrict__ K, float* __restrict__ V,
    const int* __restrict__ flag)
{
    if (*flag)
        qkv_body<float>(seq, (const float*)emb, (const float*)wq,
                        (const float*)wk, (const float*)wv, Q, K, V);
    else
        qkv_body<__hip_bfloat16>(seq, (const __hip_bfloat16*)emb, (const __hip_bfloat16*)wq,
                                 (const __hip_bfloat16*)wk, (const __hip_bfloat16*)wv, Q, K, V);
}

// ---------------------------------------------------------------------------
// Kernel 2 (R18): R15 pair-split body + SPLIT-K across two equal blocks.
// Grid (bh, pair, s): block handles tiles (63-pair) and (pair), but only the
// s-th half of each wave's chunk range -> every block ~32.5 chunk-units, all
// 512 blocks EQUAL -> any placement gives 2 blocks/CU = 4 waves/SIMD with no
// drain (R16's unequal-block placement roulette eliminated). Per-CU DS rate
// equals R12's proven-tolerable level. Blocks write per-row (O[32], m, l)
// partials (NO division) to workspace; combine_kernel merges the 2 halves.
// VGPR ~120 fits the hard 128 cap for 512-thread blocks ((1024,*) caps at
// 64 -> R17 spill; (512,2) verified no-spill since R8).
// ---------------------------------------------------------------------------
__device__ __forceinline__ void attn_tile_split(
    int qt, int s, int wid, int lane, int tid, int bh,
    const float* __restrict__ Qh, const float* __restrict__ Kh,
    const float* __restrict__ Vh, float* __restrict__ pws,
    float (*stage)[2 * CHUNK * HEAD_DIM], float (*part)[QTILE][18])
{
    const int half = lane & 1;              // 0: dims 0..15, 1: dims 16..31
    const int pr   = lane >> 1;             // 0..31 pair index
    const int rowA = qt * QTILE + pr;       // head-space rows
    const int rowB = rowA + 32;
    const float scale = 0.17677669529663687f;   // 1/sqrt(32), folded into q

    float qv0[16], qv1[16];
#pragma unroll
    for (int j4 = 0; j4 < 4; ++j4) {
        const float4 a = *(const float4*)(Qh + (size_t)rowA * HEAD_DIM + half * 16 + 4 * j4);
        const float4 b = *(const float4*)(Qh + (size_t)rowB * HEAD_DIM + half * 16 + 4 * j4);
        qv0[4*j4] = a.x*scale; qv0[4*j4+1] = a.y*scale; qv0[4*j4+2] = a.z*scale; qv0[4*j4+3] = a.w*scale;
        qv1[4*j4] = b.x*scale; qv1[4*j4+1] = b.y*scale; qv1[4*j4+2] = b.z*scale; qv1[4*j4+3] = b.w*scale;
    }

    float ov0[16], ov1[16];
#pragma unroll
    for (int j = 0; j < 16; ++j) { ov0[j] = 0.f; ov1[j] = 0.f; }
    float m0 = 0.f, l0 = 0.f, m1 = 0.f, l1 = 0.f;

    // wave's chunk range within this tile, split by s (s=0: ceil, s=1: floor)
    const int n    = qt + 1;                     // chunks per wave in this tile
    const int hcnt = (n + 1) >> 1;
    const int cnt  = (s == 0) ? hcnt : (n - hcnt);
    const int cb   = wid * n + ((s == 0) ? 0 : hcnt);

    // staging roles: lanes 0..31 -> K, lanes 32..63 -> V; 32B each
    const int sl = lane & 31;
    const float* gsrc0 = (lane < 32) ? Kh : Vh;
    float* dst = &stage[wid][((lane >= 32) ? CHUNK * HEAD_DIM : 0) + sl * 8];

    float4 pa, pb;
    {
        const float* src = gsrc0 + (size_t)cb * CHUNK * HEAD_DIM + sl * 8;
        pa = *(const float4*)(src);
        pb = *(const float4*)(src + 4);
    }

    for (int c = cb; c < cb + cnt; ++c) {
        *(float4*)(dst)     = pa;
        *(float4*)(dst + 4) = pb;
        if (c + 1 < cb + cnt) {
            const float* src = gsrc0 + (size_t)(c + 1) * CHUNK * HEAD_DIM + sl * 8;
            pa = *(const float4*)(src);
            pb = *(const float4*)(src + 4);
        }
        const int k0 = c * CHUNK;

        // ---- QK: each lane half-dots both rows, combine via DPP xor-1 ----
        float p0[CHUNK], p1[CHUNK];
        float cm0 = m0, cm1 = m1;
#pragma unroll
        for (int i = 0; i < CHUNK; ++i) {
            const float* kr = &stage[wid][i * HEAD_DIM + half * 16];
            float s0 = 0.f, s1 = 0.f;
#pragma unroll
            for (int j4 = 0; j4 < 4; ++j4) {
                const float4 kk = *(const float4*)(kr + 4 * j4);
                s0 += qv0[4*j4]*kk.x + qv0[4*j4+1]*kk.y + qv0[4*j4+2]*kk.z + qv0[4*j4+3]*kk.w;
                s1 += qv1[4*j4]*kk.x + qv1[4*j4+1]*kk.y + qv1[4*j4+2]*kk.z + qv1[4*j4+3]*kk.w;
            }
            s0 += __shfl_xor(s0, 1, 64);    // partner half (DPP, VALU pipe)
            s1 += __shfl_xor(s1, 1, 64);
            const int k = k0 + i;
            p0[i] = (k <= rowA) ? fabsf(s0) : -1.f;
            p1[i] = (k <= rowB) ? fabsf(s1) : -1.f;
            cm0 = fmaxf(cm0, p0[i]);
            cm1 = fmaxf(cm1, p1[i]);
        }
        const float a0 = __expf(m0 - cm0);
        const float a1 = __expf(m1 - cm1);
        l0 *= a0; m0 = cm0; l1 *= a1; m1 = cm1;
#pragma unroll
        for (int j = 0; j < 16; ++j) { ov0[j] *= a0; ov1[j] *= a1; }

        // ---- PV: each lane accumulates its 16-dim half for both rows ----
#pragma unroll
        for (int i = 0; i < CHUNK; ++i) {
            const float e0 = (p0[i] >= 0.f) ? __expf(p0[i] - m0) : 0.f;
            const float e1 = (p1[i] >= 0.f) ? __expf(p1[i] - m1) : 0.f;
            l0 += e0; l1 += e1;
            const float* vr = &stage[wid][CHUNK * HEAD_DIM + i * HEAD_DIM + half * 16];
#pragma unroll
            for (int j4 = 0; j4 < 4; ++j4) {
                const float4 vv = *(const float4*)(vr + 4 * j4);
                ov0[4*j4]   += e0 * vv.x; ov0[4*j4+1] += e0 * vv.y;
                ov0[4*j4+2] += e0 * vv.z; ov0[4*j4+3] += e0 * vv.w;
                ov1[4*j4]   += e1 * vv.x; ov1[4*j4+1] += e1 * vv.y;
                ov1[4*j4+2] += e1 * vv.z; ov1[4*j4+3] += e1 * vv.w;
            }
        }
    }

    // ---- in-block combine (NO division) -> per-row partial (O, m, l) ----
    float* pbase = pws + (size_t)(((bh * 64 + qt) * 2 + s) * QTILE) * PSTRIDE;
#pragma unroll
    for (int h = 0; h < 2; ++h) {
        __syncthreads();
        if (half == h) {
#pragma unroll
            for (int j = 0; j < 16; ++j) {
                part[wid][pr][j]      = ov0[j];
                part[wid][pr + 32][j] = ov1[j];
            }
            part[wid][pr][16]      = m0; part[wid][pr][17]      = l0;
            part[wid][pr + 32][16] = m1; part[wid][pr + 32][17] = l1;
        }
        __syncthreads();
        {
            const int r  = tid >> 3;       // 0..63
            const int jj = tid & 7;        // dims jj and jj+8
            float M = 0.f;
#pragma unroll
            for (int w = 0; w < NW; ++w) M = fmaxf(M, part[w][r][16]);
            float lsum = 0.f, o1 = 0.f, o2 = 0.f;
#pragma unroll
            for (int w = 0; w < NW; ++w) {
                const float a = __expf(part[w][r][16] - M);
                lsum += a * part[w][r][17];
                o1   += a * part[w][r][jj];
                o2   += a * part[w][r][jj + 8];
            }
            float* pr_ = pbase + (size_t)r * PSTRIDE;
            pr_[h * 16 + jj]     = o1;
            pr_[h * 16 + jj + 8] = o2;
            if (h == 0 && jj == 0) { pr_[32] = M; pr_[33] = lsum; }
        }
    }
}

__global__ __launch_bounds__(512, 2) void attn_kernel(
    const float* __restrict__ Q, const float* __restrict__ K,
    const float* __restrict__ V, float* __restrict__ pws)
{
    const int bh   = blockIdx.x;            // fast axis -> XCD = bh
    const int pair = blockIdx.y;            // 0..31
    const int s    = blockIdx.z;            // 0..1 split half
    const size_t base = (size_t)(bh >> 2) * SEQ * D_MODEL + (size_t)(bh & 3) * SEQ * HEAD_DIM;
    const float* Qh = Q + base;
    const float* Kh = K + base;
    const float* Vh = V + base;

    const int tid  = threadIdx.x;
    const int wid  = __builtin_amdgcn_readfirstlane(tid >> 6);
    const int lane = tid & 63;

    __shared__ __align__(16) float stage[NW][2 * CHUNK * HEAD_DIM];  // 16 KB
    __shared__ float part[NW][QTILE][18];                            // 36.9 KB

    attn_tile_split(63 - pair, s, wid, lane, tid, bh, Qh, Kh, Vh, pws, stage, part);
    attn_tile_split(pair,      s, wid, lane, tid, bh, Qh, Kh, Vh, pws, stage, part);
}

// ---------------------------------------------------------------------------
// Kernel 2b: merge the two split-k halves exactly (flash-decoding combine).
// ---------------------------------------------------------------------------
__global__ __launch_bounds__(256) void combine_kernel(
    const float* __restrict__ pws, float* __restrict__ A)
{
    const int bh = blockIdx.x;              // 0..7
    const int qt = blockIdx.y;              // 0..63
    const int tid = threadIdx.x;
    const int r  = tid >> 2;                // 0..63
    const int d8 = (tid & 3) * 8;           // dims d8..d8+7

    const float* P0 = pws + (size_t)(((bh * 64 + qt) * 2 + 0) * QTILE + r) * PSTRIDE;
    const float* P1 = pws + (size_t)(((bh * 64 + qt) * 2 + 1) * QTILE + r) * PSTRIDE;
    const float m0 = P0[32], l0 = P0[33];
    const float m1 = P1[32], l1 = P1[33];
    const float M  = fmaxf(m0, m1);
    const float a0 = __expf(m0 - M);
    const float a1 = __expf(m1 - M);
    const float L  = a0 * l0 + a1 * l1;     // > 0 (diagonal always present)
    const float invL = 1.f / L;

    const size_t base = (size_t)(bh >> 2) * SEQ * D_MODEL + (size_t)(bh & 3) * SEQ * HEAD_DIM;
    float* Ao = A + base + (size_t)(qt * QTILE + r) * HEAD_DIM + d8;
#pragma unroll
    for (int d = 0; d < 8; ++d)
        Ao[d] = (a0 * P0[d8 + d] + a1 * P1[d8 + d]) * invL;
}

// ---------------------------------------------------------------------------
// Kernel 3: out = att @ Wo^T  (RROWS=8, float4 weight loads)
// ---------------------------------------------------------------------------
template <typename T>
__device__ __forceinline__ void out_proj_body(
    const float* __restrict__ att, const T* __restrict__ wo, T* __restrict__ out)
{
    const int e = threadIdx.x;
    const int r0 = blockIdx.x * RROWS;
    __shared__ __align__(16) float xs[RROWS][D_MODEL];
#pragma unroll
    for (int r = 0; r < RROWS; ++r)
        xs[r][e] = att[(size_t)(r0 + r) * D_MODEL + e];
    __syncthreads();

    const T* wr = wo + e * D_MODEL;
    float acc[RROWS];
#pragma unroll
    for (int r = 0; r < RROWS; ++r) acc[r] = 0.f;
    for (int c = 0; c < 32; ++c) {
        const float4 w4 = load4(wr + 4 * c);
#pragma unroll
        for (int r = 0; r < RROWS; ++r) {
            const float4 x4 = *(const float4*)&xs[r][4*c];
            acc[r] += x4.x*w4.x + x4.y*w4.y + x4.z*w4.z + x4.w*w4.w;
        }
    }
#pragma unroll
    for (int r = 0; r < RROWS; ++r)
        storef(out, (size_t)(r0 + r) * D_MODEL + e, acc[r]);
}

__global__ __launch_bounds__(128) void out_proj_kernel(
    const float* __restrict__ att, const void* wo, void* out,
    const int* __restrict__ flag)
{
    if (*flag)
        out_proj_body<float>(att, (const float*)wo, (float*)out);
    else
        out_proj_body<__hip_bfloat16>(att, (const __hip_bfloat16*)wo, (__hip_bfloat16*)out);
}

extern "C" void kernel_launch(void* const* d_in, const int* in_sizes, int n_in,
                              void* d_out, int out_size, void* d_ws, size_t ws_size,
                              hipStream_t stream) {
    const int* seq = (const int*)d_in[0];
    const void* emb = d_in[1];
    const void* wq  = d_in[2];
    const void* wk  = d_in[3];
    const void* wv  = d_in[4];
    const void* wo  = d_in[5];

    const size_t N = (size_t)BATCH * SEQ * D_MODEL;   // 1,048,576
    int*   flag = (int*)d_ws;
    float* Q   = (float*)((char*)d_ws + 256);
    float* K   = Q + N;
    float* V   = K + N;
    float* pws = V + N;   // 8*64*2*64*36 floats = 9.4 MB of partials
    float* A   = Q;       // alias: combine runs after all attn blocks finish

    detect_kernel<<<dim3(1), dim3(64), 0, stream>>>((const unsigned short*)wq, flag);
    qkv_kernel<<<dim3(BATCH * SEQ / RROWS), dim3(128), 0, stream>>>(seq, emb, wq, wk, wv, Q, K, V, flag);
    attn_kernel<<<dim3(BATCH * NUM_HEAD, SEQ / QTILE / 2, 2), dim3(512), 0, stream>>>(Q, K, V, pws);
    combine_kernel<<<dim3(BATCH * NUM_HEAD, SEQ / QTILE), dim3(256), 0, stream>>>(pws, A);
    out_proj_kernel<<<dim3(BATCH * SEQ / RROWS), dim3(128), 0, stream>>>(A, wo, d_out, flag);
}

// Round 19
// 234.088 us; speedup vs baseline: 5.8299x; 1.4162x over previous
//
#include <hip/hip_runtime.h>
#include <hip/hip_bf16.h>
#include <cmath>

#define D_MODEL 128
#define NUM_HEAD 4
#define HEAD_DIM 32
#define SEQ 4096
#define BATCH 2
#define RROWS 8    // token rows per projection block

typedef __attribute__((ext_vector_type(8))) short short8;
typedef __attribute__((ext_vector_type(4))) float f32x4;

__device__ __forceinline__ float tof(float x) { return x; }
__device__ __forceinline__ float tof(__hip_bfloat16 x) { return __bfloat162float(x); }
__device__ __forceinline__ void storef(float* p, size_t i, float v) { p[i] = v; }
__device__ __forceinline__ void storef(__hip_bfloat16* p, size_t i, float v) { p[i] = __float2bfloat16(v); }
__device__ __forceinline__ float4 load4(const float* p) { return *(const float4*)p; }
__device__ __forceinline__ float4 load4(const __hip_bfloat16* p) {
    return make_float4(tof(p[0]), tof(p[1]), tof(p[2]), tof(p[3]));
}

// manual RNE split: x = hi + lo in bf16, error ~2^-18 relative
__device__ __forceinline__ void split_bf16(float x, unsigned short& hi, unsigned short& lo)
{
    const unsigned u = __float_as_uint(x);
    const unsigned r = u + 0x7FFFu + ((u >> 16) & 1u);
    hi = (unsigned short)(r >> 16);
    const float hf = __uint_as_float((unsigned)hi << 16);
    const float lf = x - hf;
    const unsigned ul = __float_as_uint(lf);
    const unsigned rl = ul + 0x7FFFu + ((ul >> 16) & 1u);
    lo = (unsigned short)(rl >> 16);
}

// ---------------------------------------------------------------------------
// Kernel 0: dtype detector (f32 vs bf16 inputs), unchanged (passes since R3).
// ---------------------------------------------------------------------------
__global__ void detect_kernel(const unsigned short* __restrict__ w, int* __restrict__ flag)
{
    const int t = threadIdx.x;   // 64 threads
    int weird = 0;
#pragma unroll
    for (int j = 0; j < 4; ++j) {
        const unsigned short v = w[(t * 4 + j) * 2 + 1];
        const float x = __uint_as_float((unsigned)v << 16);
        const float a = fabsf(x);
        if (a > 1e20f || (a > 0.f && a < 1e-20f)) weird++;
    }
#pragma unroll
    for (int off = 32; off; off >>= 1) weird += __shfl_xor(weird, off);
    if (t == 0) *flag = (weird < 32) ? 1 : 0;
}

// ---------------------------------------------------------------------------
// Kernel 1: x = embedding[seq] + PE;  Q/K/V = x @ W^T, emitted as SPLIT bf16:
// Qhi/Qlo (scale 1/sqrt(32) folded in), Khi/Klo (flat row-major = head view),
// Vthi/Vtlo (per-head TRANSPOSED [dim][k] so PV B-frags are contiguous).
// ---------------------------------------------------------------------------
template <typename T>
__device__ __forceinline__ void qkv_body(
    const int* __restrict__ seq, const T* __restrict__ emb,
    const T* __restrict__ wq, const T* __restrict__ wk, const T* __restrict__ wv,
    unsigned short* __restrict__ Qhi, unsigned short* __restrict__ Qlo,
    unsigned short* __restrict__ Khi, unsigned short* __restrict__ Klo,
    unsigned short* __restrict__ Vthi, unsigned short* __restrict__ Vtlo)
{
    const int e = threadIdx.x;               // 0..127 output dim
    const int r0 = blockIdx.x * RROWS;
    __shared__ __align__(16) float xs[RROWS][D_MODEL];

    {
        const int i = e >> 1;
        const double inv = 1.0 / pow(10000.0, (double)i / 64.0);
        const int s0 = r0 & (SEQ - 1);
        double c = cos((double)s0 * inv);
        double s = sin((double)s0 * inv);
        const double cd = cos(inv), sd = sin(inv);
        const bool odd = (e & 1);
#pragma unroll
        for (int r = 0; r < RROWS; ++r) {
            const float pe = (float)(odd ? c : s);
            xs[r][e] = tof(emb[(size_t)seq[r0 + r] * D_MODEL + e]) + pe;
            const double cn = c * cd - s * sd;
            s = s * cd + c * sd;
            c = cn;
        }
    }
    __syncthreads();

    const T* wqr = wq + e * D_MODEL;
    const T* wkr = wk + e * D_MODEL;
    const T* wvr = wv + e * D_MODEL;
    float aq[RROWS], ak[RROWS], av[RROWS];
#pragma unroll
    for (int r = 0; r < RROWS; ++r) { aq[r] = 0.f; ak[r] = 0.f; av[r] = 0.f; }

    for (int c = 0; c < 32; ++c) {
        const float4 wq4 = load4(wqr + 4 * c);
        const float4 wk4 = load4(wkr + 4 * c);
        const float4 wv4 = load4(wvr + 4 * c);
#pragma unroll
        for (int r = 0; r < RROWS; ++r) {
            const float4 x4 = *(const float4*)&xs[r][4*c];
            aq[r] += x4.x*wq4.x + x4.y*wq4.y + x4.z*wq4.z + x4.w*wq4.w;
            ak[r] += x4.x*wk4.x + x4.y*wk4.y + x4.z*wk4.z + x4.w*wk4.w;
            av[r] += x4.x*wv4.x + x4.y*wv4.y + x4.z*wv4.z + x4.w*wv4.w;
        }
    }
    const float scale = 0.17677669529663687f;   // 1/sqrt(32) folded into Q
#pragma unroll
    for (int r = 0; r < RROWS; ++r) {
        const int row = r0 + r;
        const size_t o = (size_t)row * D_MODEL + e;
        unsigned short hi, lo;
        split_bf16(aq[r] * scale, hi, lo); Qhi[o] = hi; Qlo[o] = lo;
        split_bf16(ak[r], hi, lo);         Khi[o] = hi; Klo[o] = lo;
        // V transposed per head: head h = s>>10; k = (s&1023)*4 + e/32; dim = e&31
        const int b = row >> 12, s = row & (SEQ - 1);
        const int h = s >> 10;
        const int kk = ((s & 1023) << 2) + (e >> 5);
        const int dim = e & 31;
        const size_t vt = (size_t)(b * 4 + h) * (32 * SEQ) + (size_t)dim * SEQ + kk;
        split_bf16(av[r], hi, lo);         Vthi[vt] = hi; Vtlo[vt] = lo;
    }
}

__global__ __launch_bounds__(128) void qkv_kernel(
    const int* __restrict__ seq, const void* emb,
    const void* wq, const void* wk, const void* wv,
    unsigned short* Qhi, unsigned short* Qlo,
    unsigned short* Khi, unsigned short* Klo,
    unsigned short* Vthi, unsigned short* Vtlo,
    const int* __restrict__ flag)
{
    if (*flag)
        qkv_body<float>(seq, (const float*)emb, (const float*)wq,
                        (const float*)wk, (const float*)wv, Qhi, Qlo, Khi, Klo, Vthi, Vtlo);
    else
        qkv_body<__hip_bfloat16>(seq, (const __hip_bfloat16*)emb, (const __hip_bfloat16*)wq,
                                 (const __hip_bfloat16*)wk, (const __hip_bfloat16*)wv,
                                 Qhi, Qlo, Khi, Klo, Vthi, Vtlo);
}

// ---------------------------------------------------------------------------
// Kernel 2 (R19): MFMA flash attention, split-bf16 (3 MFMAs per product,
// error ~2^-18 rel, 40x inside the 1.7e-4 threshold).
// Block = (bh, pair), 8 waves: wave = (row-tile rt = wid&3, k-half kh =
// wid>>2). Tiles 63-pair then pair sequentially: every wave runs exactly
// (qt0+1)+(qt1+1) = 65 chunks of 32 k-cols — perfect balance everywhere.
// Layouts (m89/m91/m120-verified): A[m=lane&15][k=quad*8+j]; B[k=quad*8+j]
// [n=lane&15]; C col=lane&15, row=quad*4+reg. Softmax state kept in
// C-layout (m/l rows == O rows). P transposes through per-wave LDS
// (same-wave, no barrier) and is re-split to bf16 hi/lo for PV.
// K/V^T frags are direct coalesced b128 global loads (1 MB/bh working set,
// XCD-L2 resident via bh-fast grid axis). launch_bounds(512,2) = verified
// 128-VGPR no-spill config; ~90 live VGPRs.
// ---------------------------------------------------------------------------
__global__ __launch_bounds__(512, 2) void attn_kernel(
    const unsigned short* __restrict__ Qhi, const unsigned short* __restrict__ Qlo,
    const unsigned short* __restrict__ Khi, const unsigned short* __restrict__ Klo,
    const unsigned short* __restrict__ Vthi, const unsigned short* __restrict__ Vtlo,
    float* __restrict__ A)
{
    const int bh   = blockIdx.x;            // fast axis -> XCD = bh
    const int pair = blockIdx.y;            // 0..31
    const size_t baseQ  = (size_t)(bh >> 2) * SEQ * D_MODEL + (size_t)(bh & 3) * SEQ * HEAD_DIM;
    const size_t baseVt = (size_t)bh * (32 * SEQ);

    const int tid  = threadIdx.x;
    const int wid  = __builtin_amdgcn_readfirstlane(tid >> 6);
    const int lane = tid & 63;
    const int rt   = wid & 3;               // row-tile 0..3
    const int kh   = wid >> 2;              // k-half 0..1
    const int quad = lane >> 4;
    const int col  = lane & 15;

    __shared__ float pbuf[8][16 * 34];      // per-wave P transpose: 17.4 KB
    __shared__ float comb[4][16][34];       // per-row-tile combine: 8.7 KB

#pragma unroll
    for (int ti = 0; ti < 2; ++ti) {
        const int qt = ti ? pair : (63 - pair);
        const int qrow0 = qt * 64 + rt * 16;

        // Q A-frags (once per tile): row = qrow0+col, dims quad*8..+7
        short8 qhiF, qloF;
        {
            const size_t qo = baseQ + (size_t)(qrow0 + col) * HEAD_DIM + quad * 8;
            qhiF = *(const short8*)(Qhi + qo);
            qloF = *(const short8*)(Qlo + qo);
        }

        f32x4 O0 = {0.f, 0.f, 0.f, 0.f};    // v-dims col
        f32x4 O1 = {0.f, 0.f, 0.f, 0.f};    // v-dims 16+col
        float m[4] = {0.f, 0.f, 0.f, 0.f};
        float l[4] = {0.f, 0.f, 0.f, 0.f};

        const int nch    = qt + 1;
        const int kstart = kh * nch * 32;

        for (int c = 0; c < nch; ++c) {
            const int kbase = kstart + c * 32;
            // K B-frags: n=col -> k-row kbase(+16)+col, dims quad*8..+7
            const size_t k0o = baseQ + (size_t)(kbase + col) * HEAD_DIM + quad * 8;
            const size_t k1o = baseQ + (size_t)(kbase + 16 + col) * HEAD_DIM + quad * 8;
            const short8 k0h = *(const short8*)(Khi + k0o);
            const short8 k0l = *(const short8*)(Klo + k0o);
            const short8 k1h = *(const short8*)(Khi + k1o);
            const short8 k1l = *(const short8*)(Klo + k1o);

            f32x4 s0 = {0.f, 0.f, 0.f, 0.f};
            f32x4 s1 = {0.f, 0.f, 0.f, 0.f};
            s0 = __builtin_amdgcn_mfma_f32_16x16x32_bf16(qhiF, k0h, s0, 0, 0, 0);
            s0 = __builtin_amdgcn_mfma_f32_16x16x32_bf16(qhiF, k0l, s0, 0, 0, 0);
            s0 = __builtin_amdgcn_mfma_f32_16x16x32_bf16(qloF, k0h, s0, 0, 0, 0);
            s1 = __builtin_amdgcn_mfma_f32_16x16x32_bf16(qhiF, k1h, s1, 0, 0, 0);
            s1 = __builtin_amdgcn_mfma_f32_16x16x32_bf16(qhiF, k1l, s1, 0, 0, 0);
            s1 = __builtin_amdgcn_mfma_f32_16x16x32_bf16(qloF, k1h, s1, 0, 0, 0);

            // abs + causal mask in C-layout; chunk max
            float p0[4], p1[4], cm[4];
#pragma unroll
            for (int r = 0; r < 4; ++r) {
                const int rowg = qrow0 + quad * 4 + r;
                p0[r] = (kbase + col      <= rowg) ? fabsf(s0[r]) : -1.f;
                p1[r] = (kbase + 16 + col <= rowg) ? fabsf(s1[r]) : -1.f;
                cm[r] = fmaxf(p0[r], p1[r]);
            }
#pragma unroll
            for (int off = 1; off < 16; off <<= 1) {
#pragma unroll
                for (int r = 0; r < 4; ++r) cm[r] = fmaxf(cm[r], __shfl_xor(cm[r], off, 64));
            }
#pragma unroll
            for (int r = 0; r < 4; ++r) {
                const float nm = fmaxf(m[r], cm[r]);
                const float al = __expf(m[r] - nm);   // ==1 when unchanged
                l[r] *= al; O0[r] *= al; O1[r] *= al; m[r] = nm;
            }
            // P = exp(p - m), write to per-wave LDS in [row][k] form
#pragma unroll
            for (int r = 0; r < 4; ++r) {
                const float e0 = (p0[r] >= 0.f) ? __expf(p0[r] - m[r]) : 0.f;
                const float e1 = (p1[r] >= 0.f) ? __expf(p1[r] - m[r]) : 0.f;
                l[r] += e0 + e1;
                pbuf[wid][(quad * 4 + r) * 34 + col]      = e0;
                pbuf[wid][(quad * 4 + r) * 34 + 16 + col] = e1;
            }
            // read back as A-frag (row=col, k=quad*8..+7) and split to bf16
            short8 ph, pl;
            {
                const float* pr = &pbuf[wid][col * 34 + quad * 8];
#pragma unroll
                for (int j = 0; j < 8; ++j) {
                    unsigned short h_, l_;
                    split_bf16(pr[j], h_, l_);
                    ph[j] = (short)h_; pl[j] = (short)l_;
                }
            }
            // V^T B-frags: n=col -> v-dim col / 16+col, k = kbase+quad*8..+7
            const size_t v0o = baseVt + (size_t)col * SEQ + kbase + quad * 8;
            const size_t v1o = baseVt + (size_t)(16 + col) * SEQ + kbase + quad * 8;
            const short8 v0h = *(const short8*)(Vthi + v0o);
            const short8 v0l = *(const short8*)(Vtlo + v0o);
            const short8 v1h = *(const short8*)(Vthi + v1o);
            const short8 v1l = *(const short8*)(Vtlo + v1o);

            O0 = __builtin_amdgcn_mfma_f32_16x16x32_bf16(ph, v0h, O0, 0, 0, 0);
            O0 = __builtin_amdgcn_mfma_f32_16x16x32_bf16(ph, v0l, O0, 0, 0, 0);
            O0 = __builtin_amdgcn_mfma_f32_16x16x32_bf16(pl, v0h, O0, 0, 0, 0);
            O1 = __builtin_amdgcn_mfma_f32_16x16x32_bf16(ph, v1h, O1, 0, 0, 0);
            O1 = __builtin_amdgcn_mfma_f32_16x16x32_bf16(ph, v1l, O1, 0, 0, 0);
            O1 = __builtin_amdgcn_mfma_f32_16x16x32_bf16(pl, v1h, O1, 0, 0, 0);
        }

        // finalize l: sum over the 16-lane col group
#pragma unroll
        for (int off = 1; off < 16; off <<= 1) {
#pragma unroll
            for (int r = 0; r < 4; ++r) l[r] += __shfl_xor(l[r], off, 64);
        }

        // exact cross-k-half combine via LDS
        __syncthreads();
        if (kh == 0) {
#pragma unroll
            for (int r = 0; r < 4; ++r) {
                const int row = quad * 4 + r;
                comb[rt][row][col]      = O0[r];
                comb[rt][row][16 + col] = O1[r];
            }
            if (col == 0) {
#pragma unroll
                for (int r = 0; r < 4; ++r) {
                    comb[rt][quad * 4 + r][32] = m[r];
                    comb[rt][quad * 4 + r][33] = l[r];
                }
            }
        }
        __syncthreads();
        if (kh == 1) {
#pragma unroll
            for (int r = 0; r < 4; ++r) {
                const int row = quad * 4 + r;
                const float pm  = comb[rt][row][32];
                const float pl_ = comb[rt][row][33];
                const float M  = fmaxf(m[r], pm);
                const float a0 = __expf(pm - M);
                const float a1 = __expf(m[r] - M);
                const float invL = 1.f / (a0 * pl_ + a1 * l[r]);
                const float o0 = (a0 * comb[rt][row][col]      + a1 * O0[r]) * invL;
                const float o1 = (a0 * comb[rt][row][16 + col] + a1 * O1[r]) * invL;
                A[baseQ + (size_t)(qrow0 + row) * HEAD_DIM + col]      = o0;
                A[baseQ + (size_t)(qrow0 + row) * HEAD_DIM + 16 + col] = o1;
            }
        }
        __syncthreads();   // protect comb before next tile
    }
}

// ---------------------------------------------------------------------------
// Kernel 3: out = att @ Wo^T  (RROWS=8, float4 weight loads)
// ---------------------------------------------------------------------------
template <typename T>
__device__ __forceinline__ void out_proj_body(
    const float* __restrict__ att, const T* __restrict__ wo, T* __restrict__ out)
{
    const int e = threadIdx.x;
    const int r0 = blockIdx.x * RROWS;
    __shared__ __align__(16) float xs[RROWS][D_MODEL];
#pragma unroll
    for (int r = 0; r < RROWS; ++r)
        xs[r][e] = att[(size_t)(r0 + r) * D_MODEL + e];
    __syncthreads();

    const T* wr = wo + e * D_MODEL;
    float acc[RROWS];
#pragma unroll
    for (int r = 0; r < RROWS; ++r) acc[r] = 0.f;
    for (int c = 0; c < 32; ++c) {
        const float4 w4 = load4(wr + 4 * c);
#pragma unroll
        for (int r = 0; r < RROWS; ++r) {
            const float4 x4 = *(const float4*)&xs[r][4*c];
            acc[r] += x4.x*w4.x + x4.y*w4.y + x4.z*w4.z + x4.w*w4.w;
        }
    }
#pragma unroll
    for (int r = 0; r < RROWS; ++r)
        storef(out, (size_t)(r0 + r) * D_MODEL + e, acc[r]);
}

__global__ __launch_bounds__(128) void out_proj_kernel(
    const float* __restrict__ att, const void* wo, void* out,
    const int* __restrict__ flag)
{
    if (*flag)
        out_proj_body<float>(att, (const float*)wo, (float*)out);
    else
        out_proj_body<__hip_bfloat16>(att, (const __hip_bfloat16*)wo, (__hip_bfloat16*)out);
}

extern "C" void kernel_launch(void* const* d_in, const int* in_sizes, int n_in,
                              void* d_out, int out_size, void* d_ws, size_t ws_size,
                              hipStream_t stream) {
    const int* seq = (const int*)d_in[0];
    const void* emb = d_in[1];
    const void* wq  = d_in[2];
    const void* wk  = d_in[3];
    const void* wv  = d_in[4];
    const void* wo  = d_in[5];

    const size_t N = (size_t)BATCH * SEQ * D_MODEL;   // 1,048,576 elements
    int*            flag = (int*)d_ws;
    unsigned short* Qhi  = (unsigned short*)((char*)d_ws + 256);
    unsigned short* Qlo  = Qhi + N;
    unsigned short* Khi  = Qlo + N;
    unsigned short* Klo  = Khi + N;
    unsigned short* Vthi = Klo + N;
    unsigned short* Vtlo = Vthi + N;
    float*          A    = (float*)(Vtlo + N);        // fp32 attn output (4 MB)

    detect_kernel<<<dim3(1), dim3(64), 0, stream>>>((const unsigned short*)wq, flag);
    qkv_kernel<<<dim3(BATCH * SEQ / RROWS), dim3(128), 0, stream>>>(
        seq, emb, wq, wk, wv, Qhi, Qlo, Khi, Klo, Vthi, Vtlo, flag);
    attn_kernel<<<dim3(BATCH * NUM_HEAD, 32), dim3(512), 0, stream>>>(
        Qhi, Qlo, Khi, Klo, Vthi, Vtlo, A);
    out_proj_kernel<<<dim3(BATCH * SEQ / RROWS), dim3(128), 0, stream>>>(A, wo, d_out, flag);
}

// Round 20
// 216.594 us; speedup vs baseline: 6.3007x; 1.0808x over previous
//
#include <hip/hip_runtime.h>
#include <hip/hip_bf16.h>
#include <cmath>

#define D_MODEL 128
#define NUM_HEAD 4
#define HEAD_DIM 32
#define SEQ 4096
#define BATCH 2
#define RROWS 8    // token rows per projection block

typedef __attribute__((ext_vector_type(8))) short short8;
typedef __attribute__((ext_vector_type(4))) float f32x4;

__device__ __forceinline__ float tof(float x) { return x; }
__device__ __forceinline__ float tof(__hip_bfloat16 x) { return __bfloat162float(x); }
__device__ __forceinline__ void storef(float* p, size_t i, float v) { p[i] = v; }
__device__ __forceinline__ void storef(__hip_bfloat16* p, size_t i, float v) { p[i] = __float2bfloat16(v); }
__device__ __forceinline__ float4 load4(const float* p) { return *(const float4*)p; }
__device__ __forceinline__ float4 load4(const __hip_bfloat16* p) {
    return make_float4(tof(p[0]), tof(p[1]), tof(p[2]), tof(p[3]));
}

// manual RNE split: x = hi + lo in bf16, error ~2^-18 relative
__device__ __forceinline__ void split_bf16(float x, unsigned short& hi, unsigned short& lo)
{
    const unsigned u = __float_as_uint(x);
    const unsigned r = u + 0x7FFFu + ((u >> 16) & 1u);
    hi = (unsigned short)(r >> 16);
    const float hf = __uint_as_float((unsigned)hi << 16);
    const float lf = x - hf;
    const unsigned ul = __float_as_uint(lf);
    const unsigned rl = ul + 0x7FFFu + ((ul >> 16) & 1u);
    lo = (unsigned short)(rl >> 16);
}
// hi-only RNE round (for P, whose lo term is dropped in PV)
__device__ __forceinline__ unsigned short rne_bf16(float x)
{
    const unsigned u = __float_as_uint(x);
    return (unsigned short)((u + 0x7FFFu + ((u >> 16) & 1u)) >> 16);
}

// ---------------------------------------------------------------------------
// Kernel 0: dtype detector (f32 vs bf16 inputs), unchanged (passes since R3).
// ---------------------------------------------------------------------------
__global__ void detect_kernel(const unsigned short* __restrict__ w, int* __restrict__ flag)
{
    const int t = threadIdx.x;   // 64 threads
    int weird = 0;
#pragma unroll
    for (int j = 0; j < 4; ++j) {
        const unsigned short v = w[(t * 4 + j) * 2 + 1];
        const float x = __uint_as_float((unsigned)v << 16);
        const float a = fabsf(x);
        if (a > 1e20f || (a > 0.f && a < 1e-20f)) weird++;
    }
#pragma unroll
    for (int off = 32; off; off >>= 1) weird += __shfl_xor(weird, off);
    if (t == 0) *flag = (weird < 32) ? 1 : 0;
}

// ---------------------------------------------------------------------------
// Kernel 1: x = embedding[seq] + PE;  Q/K/V = x @ W^T, emitted as SPLIT bf16.
// R20: V^T store re-tiled through LDS -> each thread writes one contiguous
// 16B segment per buffer (R19 scattered 16 x 2B stores/thread).
// ---------------------------------------------------------------------------
template <typename T>
__device__ __forceinline__ void qkv_body(
    const int* __restrict__ seq, const T* __restrict__ emb,
    const T* __restrict__ wq, const T* __restrict__ wk, const T* __restrict__ wv,
    unsigned short* __restrict__ Qhi, unsigned short* __restrict__ Qlo,
    unsigned short* __restrict__ Khi, unsigned short* __restrict__ Klo,
    unsigned short* __restrict__ Vthi, unsigned short* __restrict__ Vtlo)
{
    const int e = threadIdx.x;               // 0..127 output dim
    const int r0 = blockIdx.x * RROWS;
    __shared__ __align__(16) float xs[RROWS][D_MODEL];
    __shared__ __align__(16) unsigned short vsh[2][RROWS][D_MODEL];

    {
        const int i = e >> 1;
        const double inv = 1.0 / pow(10000.0, (double)i / 64.0);
        const int s0 = r0 & (SEQ - 1);
        double c = cos((double)s0 * inv);
        double s = sin((double)s0 * inv);
        const double cd = cos(inv), sd = sin(inv);
        const bool odd = (e & 1);
#pragma unroll
        for (int r = 0; r < RROWS; ++r) {
            const float pe = (float)(odd ? c : s);
            xs[r][e] = tof(emb[(size_t)seq[r0 + r] * D_MODEL + e]) + pe;
            const double cn = c * cd - s * sd;
            s = s * cd + c * sd;
            c = cn;
        }
    }
    __syncthreads();

    const T* wqr = wq + e * D_MODEL;
    const T* wkr = wk + e * D_MODEL;
    const T* wvr = wv + e * D_MODEL;
    float aq[RROWS], ak[RROWS], av[RROWS];
#pragma unroll
    for (int r = 0; r < RROWS; ++r) { aq[r] = 0.f; ak[r] = 0.f; av[r] = 0.f; }

    for (int c = 0; c < 32; ++c) {
        const float4 wq4 = load4(wqr + 4 * c);
        const float4 wk4 = load4(wkr + 4 * c);
        const float4 wv4 = load4(wvr + 4 * c);
#pragma unroll
        for (int r = 0; r < RROWS; ++r) {
            const float4 x4 = *(const float4*)&xs[r][4*c];
            aq[r] += x4.x*wq4.x + x4.y*wq4.y + x4.z*wq4.z + x4.w*wq4.w;
            ak[r] += x4.x*wk4.x + x4.y*wk4.y + x4.z*wk4.z + x4.w*wk4.w;
            av[r] += x4.x*wv4.x + x4.y*wv4.y + x4.z*wv4.z + x4.w*wv4.w;
        }
    }
    const float scale = 0.17677669529663687f;   // 1/sqrt(32) folded into Q
#pragma unroll
    for (int r = 0; r < RROWS; ++r) {
        const size_t o = (size_t)(r0 + r) * D_MODEL + e;
        unsigned short hi, lo;
        split_bf16(aq[r] * scale, hi, lo); Qhi[o] = hi; Qlo[o] = lo;
        split_bf16(ak[r], hi, lo);         Khi[o] = hi; Klo[o] = lo;
        split_bf16(av[r], hi, lo);         vsh[0][r][e] = hi; vsh[1][r][e] = lo;
    }
    __syncthreads();

    // coalesced V^T store: head-row k = (s&1023)*4 + e/32, head-dim = e&31
    {
        const int b  = r0 >> 12;
        const int s0 = r0 & (SEQ - 1);
        const int h  = s0 >> 10;
        const size_t vtb = (size_t)(b * 4 + h) * (32 * SEQ);
        const int d = e >> 2;                // 0..31 head-dim
        const int j = e & 3;                 // 8-k segment within the block's 32 k's
        const int kk0 = (s0 & 1023) << 2;
#pragma unroll
        for (int hl = 0; hl < 2; ++hl) {
            short8 tmp;
#pragma unroll
            for (int i = 0; i < 8; ++i) {
                const int kl = j * 8 + i;    // 0..31 local k
                tmp[i] = (short)vsh[hl][kl >> 2][(kl & 3) * 32 + d];
            }
            unsigned short* dst = (hl ? Vtlo : Vthi) + vtb + (size_t)d * SEQ + kk0 + j * 8;
            *(short8*)dst = tmp;
        }
    }
}

__global__ __launch_bounds__(128) void qkv_kernel(
    const int* __restrict__ seq, const void* emb,
    const void* wq, const void* wk, const void* wv,
    unsigned short* Qhi, unsigned short* Qlo,
    unsigned short* Khi, unsigned short* Klo,
    unsigned short* Vthi, unsigned short* Vtlo,
    const int* __restrict__ flag)
{
    if (*flag)
        qkv_body<float>(seq, (const float*)emb, (const float*)wq,
                        (const float*)wk, (const float*)wv, Qhi, Qlo, Khi, Klo, Vthi, Vtlo);
    else
        qkv_body<__hip_bfloat16>(seq, (const __hip_bfloat16*)emb, (const __hip_bfloat16*)wq,
                                 (const __hip_bfloat16*)wk, (const __hip_bfloat16*)wv,
                                 Qhi, Qlo, Khi, Klo, Vthi, Vtlo);
}

// ---------------------------------------------------------------------------
// Kernel 2 (R20): MFMA flash attention, 1024-thread block = 16 waves =
// 4 waves/SIMD guaranteed (R19 body used only 48 VGPR -> fits the 64-cap of
// 1024-thr blocks; R17's spill was a 120-reg body). Wave = (rt 0..3, kh
// 0..3): kh quarters of each tile's 2*(qt+1) chunks, remainder to low kh ->
// 32-33 chunks/wave over the pair everywhere. PV drops the P-lo term
// (error ~2e-3 at out, 30x inside threshold): 6 QK + 4 PV MFMAs per chunk,
// P-split 24 ops. pbuf/comb share one 35.8KB LDS union (barrier-separated).
// 4-way kh combine (exact, flash-decoding style) writes f32 A.
// ---------------------------------------------------------------------------
__global__ __launch_bounds__(1024, 1) void attn_kernel(
    const unsigned short* __restrict__ Qhi, const unsigned short* __restrict__ Qlo,
    const unsigned short* __restrict__ Khi, const unsigned short* __restrict__ Klo,
    const unsigned short* __restrict__ Vthi, const unsigned short* __restrict__ Vtlo,
    float* __restrict__ A)
{
    const int bh   = blockIdx.x;            // fast axis -> XCD = bh
    const int pair = blockIdx.y;            // 0..31
    const size_t baseQ  = (size_t)(bh >> 2) * SEQ * D_MODEL + (size_t)(bh & 3) * SEQ * HEAD_DIM;
    const size_t baseVt = (size_t)bh * (32 * SEQ);

    const int tid  = threadIdx.x;
    const int wid  = __builtin_amdgcn_readfirstlane(tid >> 6);  // 0..15
    const int lane = tid & 63;
    const int rt   = wid & 3;               // row-tile 0..3
    const int kh   = wid >> 2;              // k-quarter 0..3
    const int quad = lane >> 4;
    const int col  = lane & 15;

    // union: per-wave P-transpose (stride 34) during the loop; per-(rt,kh)
    // combine partials (stride 35: O[32], m, l) after the barrier. 35.8 KB.
    __shared__ float shbuf[16 * 560];
    float* pb = &shbuf[wid * 560];

#pragma unroll
    for (int ti = 0; ti < 2; ++ti) {
        const int qt = ti ? pair : (63 - pair);
        const int qrow0 = qt * 64 + rt * 16;

        short8 qhiF, qloF;
        {
            const size_t qo = baseQ + (size_t)(qrow0 + col) * HEAD_DIM + quad * 8;
            qhiF = *(const short8*)(Qhi + qo);
            qloF = *(const short8*)(Qlo + qo);
        }

        f32x4 O0 = {0.f, 0.f, 0.f, 0.f};
        f32x4 O1 = {0.f, 0.f, 0.f, 0.f};
        float m[4] = {0.f, 0.f, 0.f, 0.f};
        float l[4] = {0.f, 0.f, 0.f, 0.f};

        const int N   = 2 * (qt + 1);       // 32-col chunks in this tile
        const int nb  = N >> 2, rem = N & 3;
        const int cnt  = nb + ((kh < rem) ? 1 : 0);
        const int cbeg = kh * nb + ((kh < rem) ? kh : rem);

        for (int c = cbeg; c < cbeg + cnt; ++c) {
            const int kbase = c * 32;
            const size_t k0o = baseQ + (size_t)(kbase + col) * HEAD_DIM + quad * 8;
            const size_t k1o = baseQ + (size_t)(kbase + 16 + col) * HEAD_DIM + quad * 8;
            const short8 k0h = *(const short8*)(Khi + k0o);
            const short8 k0l = *(const short8*)(Klo + k0o);
            const short8 k1h = *(const short8*)(Khi + k1o);
            const short8 k1l = *(const short8*)(Klo + k1o);

            f32x4 s0 = {0.f, 0.f, 0.f, 0.f};
            f32x4 s1 = {0.f, 0.f, 0.f, 0.f};
            s0 = __builtin_amdgcn_mfma_f32_16x16x32_bf16(qhiF, k0h, s0, 0, 0, 0);
            s0 = __builtin_amdgcn_mfma_f32_16x16x32_bf16(qhiF, k0l, s0, 0, 0, 0);
            s0 = __builtin_amdgcn_mfma_f32_16x16x32_bf16(qloF, k0h, s0, 0, 0, 0);
            s1 = __builtin_amdgcn_mfma_f32_16x16x32_bf16(qhiF, k1h, s1, 0, 0, 0);
            s1 = __builtin_amdgcn_mfma_f32_16x16x32_bf16(qhiF, k1l, s1, 0, 0, 0);
            s1 = __builtin_amdgcn_mfma_f32_16x16x32_bf16(qloF, k1h, s1, 0, 0, 0);

            float p0[4], p1[4], cm[4];
#pragma unroll
            for (int r = 0; r < 4; ++r) {
                const int rowg = qrow0 + quad * 4 + r;
                p0[r] = (kbase + col      <= rowg) ? fabsf(s0[r]) : -1.f;
                p1[r] = (kbase + 16 + col <= rowg) ? fabsf(s1[r]) : -1.f;
                cm[r] = fmaxf(p0[r], p1[r]);
            }
#pragma unroll
            for (int off = 1; off < 16; off <<= 1) {
#pragma unroll
                for (int r = 0; r < 4; ++r) cm[r] = fmaxf(cm[r], __shfl_xor(cm[r], off, 64));
            }
#pragma unroll
            for (int r = 0; r < 4; ++r) {
                const float nm = fmaxf(m[r], cm[r]);
                const float al = __expf(m[r] - nm);
                l[r] *= al; O0[r] *= al; O1[r] *= al; m[r] = nm;
            }
#pragma unroll
            for (int r = 0; r < 4; ++r) {
                const float e0 = (p0[r] >= 0.f) ? __expf(p0[r] - m[r]) : 0.f;
                const float e1 = (p1[r] >= 0.f) ? __expf(p1[r] - m[r]) : 0.f;
                l[r] += e0 + e1;
                pb[(quad * 4 + r) * 34 + col]      = e0;
                pb[(quad * 4 + r) * 34 + 16 + col] = e1;
            }
            short8 ph;
            {
                const float* pr = &pb[col * 34 + quad * 8];
#pragma unroll
                for (int j = 0; j < 8; ++j) ph[j] = (short)rne_bf16(pr[j]);
            }
            const size_t v0o = baseVt + (size_t)col * SEQ + kbase + quad * 8;
            const size_t v1o = baseVt + (size_t)(16 + col) * SEQ + kbase + quad * 8;
            const short8 v0h = *(const short8*)(Vthi + v0o);
            const short8 v0l = *(const short8*)(Vtlo + v0o);
            const short8 v1h = *(const short8*)(Vthi + v1o);
            const short8 v1l = *(const short8*)(Vtlo + v1o);

            O0 = __builtin_amdgcn_mfma_f32_16x16x32_bf16(ph, v0h, O0, 0, 0, 0);
            O0 = __builtin_amdgcn_mfma_f32_16x16x32_bf16(ph, v0l, O0, 0, 0, 0);
            O1 = __builtin_amdgcn_mfma_f32_16x16x32_bf16(ph, v1h, O1, 0, 0, 0);
            O1 = __builtin_amdgcn_mfma_f32_16x16x32_bf16(ph, v1l, O1, 0, 0, 0);
        }

        // finalize l: row-sum over the 16 col lanes
#pragma unroll
        for (int off = 1; off < 16; off <<= 1) {
#pragma unroll
            for (int r = 0; r < 4; ++r) l[r] += __shfl_xor(l[r], off, 64);
        }

        __syncthreads();   // all waves done with pb -> union becomes comb
        {
            float* cb = &shbuf[(rt * 4 + kh) * 560];  // stride 35 per row
#pragma unroll
            for (int r = 0; r < 4; ++r) {
                const int row = quad * 4 + r;
                cb[row * 35 + col]      = O0[r];
                cb[row * 35 + 16 + col] = O1[r];
            }
            if (col == 0) {
#pragma unroll
                for (int r = 0; r < 4; ++r) {
                    cb[(quad * 4 + r) * 35 + 32] = m[r];
                    cb[(quad * 4 + r) * 35 + 33] = l[r];
                }
            }
        }
        __syncthreads();
        if (kh == 0) {                       // 4 waves combine 4 quarters
            const int row = lane >> 2;       // 0..15
            const int d8  = (lane & 3) * 8;
            float M = 0.f;
#pragma unroll
            for (int q = 0; q < 4; ++q)
                M = fmaxf(M, shbuf[(rt * 4 + q) * 560 + row * 35 + 32]);
            float a[4], L = 0.f;
#pragma unroll
            for (int q = 0; q < 4; ++q) {
                a[q] = __expf(shbuf[(rt * 4 + q) * 560 + row * 35 + 32] - M);
                L += a[q] * shbuf[(rt * 4 + q) * 560 + row * 35 + 33];
            }
            const float invL = 1.f / L;
            float* Ao = A + baseQ + (size_t)(qrow0 + row) * HEAD_DIM + d8;
#pragma unroll
            for (int d = 0; d < 8; ++d) {
                float o = 0.f;
#pragma unroll
                for (int q = 0; q < 4; ++q)
                    o += a[q] * shbuf[(rt * 4 + q) * 560 + row * 35 + d8 + d];
                Ao[d] = o * invL;
            }
        }
        __syncthreads();   // protect shbuf before next tile
    }
}

// ---------------------------------------------------------------------------
// Kernel 3: out = att @ Wo^T  (RROWS=8, float4 weight loads)
// ---------------------------------------------------------------------------
template <typename T>
__device__ __forceinline__ void out_proj_body(
    const float* __restrict__ att, const T* __restrict__ wo, T* __restrict__ out)
{
    const int e = threadIdx.x;
    const int r0 = blockIdx.x * RROWS;
    __shared__ __align__(16) float xs[RROWS][D_MODEL];
#pragma unroll
    for (int r = 0; r < RROWS; ++r)
        xs[r][e] = att[(size_t)(r0 + r) * D_MODEL + e];
    __syncthreads();

    const T* wr = wo + e * D_MODEL;
    float acc[RROWS];
#pragma unroll
    for (int r = 0; r < RROWS; ++r) acc[r] = 0.f;
    for (int c = 0; c < 32; ++c) {
        const float4 w4 = load4(wr + 4 * c);
#pragma unroll
        for (int r = 0; r < RROWS; ++r) {
            const float4 x4 = *(const float4*)&xs[r][4*c];
            acc[r] += x4.x*w4.x + x4.y*w4.y + x4.z*w4.z + x4.w*w4.w;
        }
    }
#pragma unroll
    for (int r = 0; r < RROWS; ++r)
        storef(out, (size_t)(r0 + r) * D_MODEL + e, acc[r]);
}

__global__ __launch_bounds__(128) void out_proj_kernel(
    const float* __restrict__ att, const void* wo, void* out,
    const int* __restrict__ flag)
{
    if (*flag)
        out_proj_body<float>(att, (const float*)wo, (float*)out);
    else
        out_proj_body<__hip_bfloat16>(att, (const __hip_bfloat16*)wo, (__hip_bfloat16*)out);
}

extern "C" void kernel_launch(void* const* d_in, const int* in_sizes, int n_in,
                              void* d_out, int out_size, void* d_ws, size_t ws_size,
                              hipStream_t stream) {
    const int* seq = (const int*)d_in[0];
    const void* emb = d_in[1];
    const void* wq  = d_in[2];
    const void* wk  = d_in[3];
    const void* wv  = d_in[4];
    const void* wo  = d_in[5];

    const size_t N = (size_t)BATCH * SEQ * D_MODEL;   // 1,048,576 elements
    int*            flag = (int*)d_ws;
    unsigned short* Qhi  = (unsigned short*)((char*)d_ws + 256);
    unsigned short* Qlo  = Qhi + N;
    unsigned short* Khi  = Qlo + N;
    unsigned short* Klo  = Khi + N;
    unsigned short* Vthi = Klo + N;
    unsigned short* Vtlo = Vthi + N;
    float*          A    = (float*)(Vtlo + N);        // fp32 attn output (4 MB)

    detect_kernel<<<dim3(1), dim3(64), 0, stream>>>((const unsigned short*)wq, flag);
    qkv_kernel<<<dim3(BATCH * SEQ / RROWS), dim3(128), 0, stream>>>(
        seq, emb, wq, wk, wv, Qhi, Qlo, Khi, Klo, Vthi, Vtlo, flag);
    attn_kernel<<<dim3(BATCH * NUM_HEAD, 32), dim3(1024), 0, stream>>>(
        Qhi, Qlo, Khi, Klo, Vthi, Vtlo, A);
    out_proj_kernel<<<dim3(BATCH * SEQ / RROWS), dim3(128), 0, stream>>>(A, wo, d_out, flag);
}

// Round 21
// 193.732 us; speedup vs baseline: 7.0443x; 1.1180x over previous
//
#include <hip/hip_runtime.h>
#include <hip/hip_bf16.h>
#include <cmath>

#define D_MODEL 128
#define NUM_HEAD 4
#define HEAD_DIM 32
#define SEQ 4096
#define BATCH 2
#define RROWS 8    // token rows per projection block

typedef __attribute__((ext_vector_type(8))) short short8;
typedef __attribute__((ext_vector_type(4))) float f32x4;

__device__ __forceinline__ float tof(float x) { return x; }
__device__ __forceinline__ float tof(__hip_bfloat16 x) { return __bfloat162float(x); }
__device__ __forceinline__ void storef(float* p, size_t i, float v) { p[i] = v; }
__device__ __forceinline__ void storef(__hip_bfloat16* p, size_t i, float v) { p[i] = __float2bfloat16(v); }

// manual RNE split: x = hi + lo in bf16, error ~2^-18 relative
__device__ __forceinline__ void split_bf16(float x, unsigned short& hi, unsigned short& lo)
{
    const unsigned u = __float_as_uint(x);
    const unsigned r = u + 0x7FFFu + ((u >> 16) & 1u);
    hi = (unsigned short)(r >> 16);
    const float hf = __uint_as_float((unsigned)hi << 16);
    const float lf = x - hf;
    const unsigned ul = __float_as_uint(lf);
    const unsigned rl = ul + 0x7FFFu + ((ul >> 16) & 1u);
    lo = (unsigned short)(rl >> 16);
}
// hi-only RNE round (for P, whose lo term is dropped in PV)
__device__ __forceinline__ unsigned short rne_bf16(float x)
{
    const unsigned u = __float_as_uint(x);
    return (unsigned short)((u + 0x7FFFu + ((u >> 16) & 1u)) >> 16);
}

// ---------------------------------------------------------------------------
// Kernel 0: dtype detector (f32 vs bf16 inputs), unchanged (passes since R3).
// ---------------------------------------------------------------------------
__global__ void detect_kernel(const unsigned short* __restrict__ w, int* __restrict__ flag)
{
    const int t = threadIdx.x;   // 64 threads
    int weird = 0;
#pragma unroll
    for (int j = 0; j < 4; ++j) {
        const unsigned short v = w[(t * 4 + j) * 2 + 1];
        const float x = __uint_as_float((unsigned)v << 16);
        const float a = fabsf(x);
        if (a > 1e20f || (a > 0.f && a < 1e-20f)) weird++;
    }
#pragma unroll
    for (int off = 32; off; off >>= 1) weird += __shfl_xor(weird, off);
    if (t == 0) *flag = (weird < 32) ? 1 : 0;
}

// ---------------------------------------------------------------------------
// Kernel 0b (R21): transpose all 4 weight mats to f32 Wt[d][e] so projection
// kernels read them lane-coalesced (the e*128 row reads were 64 cachelines
// per wave instruction — the diagnosed ~80us non-attn transaction tax).
// ---------------------------------------------------------------------------
__global__ __launch_bounds__(256) void wt_kernel(
    const void* w0, const void* w1, const void* w2, const void* w3,
    float* __restrict__ wt, const int* __restrict__ flag)
{
    const int m   = blockIdx.x;                       // 0..3 (wq,wk,wv,wo)
    const int idx = blockIdx.y * 256 + threadIdx.x;   // 0..16383
    const void* w = (m == 0) ? w0 : (m == 1) ? w1 : (m == 2) ? w2 : w3;
    const int e = idx >> 7, d = idx & 127;
    const float v = (*flag) ? ((const float*)w)[idx]
                            : tof(((const __hip_bfloat16*)w)[idx]);
    wt[(size_t)m * 16384 + (size_t)d * 128 + e] = v;
}

// ---------------------------------------------------------------------------
// Kernel 1: x = embedding[seq] + PE;  Q/K/V = x @ W^T, emitted as SPLIT bf16.
// R21: weights read from pre-transposed f32 Wt (coalesced 256B/instr).
// ---------------------------------------------------------------------------
template <typename T>
__device__ __forceinline__ void qkv_body(
    const int* __restrict__ seq, const T* __restrict__ emb,
    const float* __restrict__ wqt, const float* __restrict__ wkt,
    const float* __restrict__ wvt,
    unsigned short* __restrict__ Qhi, unsigned short* __restrict__ Qlo,
    unsigned short* __restrict__ Khi, unsigned short* __restrict__ Klo,
    unsigned short* __restrict__ Vthi, unsigned short* __restrict__ Vtlo)
{
    const int e = threadIdx.x;               // 0..127 output dim
    const int r0 = blockIdx.x * RROWS;
    __shared__ __align__(16) float xs[RROWS][D_MODEL];
    __shared__ __align__(16) unsigned short vsh[2][RROWS][D_MODEL];

    {
        const int i = e >> 1;
        const double inv = 1.0 / pow(10000.0, (double)i / 64.0);
        const int s0 = r0 & (SEQ - 1);
        double c = cos((double)s0 * inv);
        double s = sin((double)s0 * inv);
        const double cd = cos(inv), sd = sin(inv);
        const bool odd = (e & 1);
#pragma unroll
        for (int r = 0; r < RROWS; ++r) {
            const float pe = (float)(odd ? c : s);
            xs[r][e] = tof(emb[(size_t)seq[r0 + r] * D_MODEL + e]) + pe;
            const double cn = c * cd - s * sd;
            s = s * cd + c * sd;
            c = cn;
        }
    }
    __syncthreads();

    float aq[RROWS], ak[RROWS], av[RROWS];
#pragma unroll
    for (int r = 0; r < RROWS; ++r) { aq[r] = 0.f; ak[r] = 0.f; av[r] = 0.f; }

    for (int d = 0; d < D_MODEL; d += 4) {
        float4 xr[RROWS];
#pragma unroll
        for (int r = 0; r < RROWS; ++r) xr[r] = *(const float4*)&xs[r][d];
#pragma unroll
        for (int dd = 0; dd < 4; ++dd) {
            const float wq_ = wqt[(size_t)(d + dd) * 128 + e];   // coalesced
            const float wk_ = wkt[(size_t)(d + dd) * 128 + e];
            const float wv_ = wvt[(size_t)(d + dd) * 128 + e];
#pragma unroll
            for (int r = 0; r < RROWS; ++r) {
                const float x = (dd == 0) ? xr[r].x : (dd == 1) ? xr[r].y
                              : (dd == 2) ? xr[r].z : xr[r].w;
                aq[r] += x * wq_; ak[r] += x * wk_; av[r] += x * wv_;
            }
        }
    }
    const float scale = 0.17677669529663687f;   // 1/sqrt(32) folded into Q
#pragma unroll
    for (int r = 0; r < RROWS; ++r) {
        const size_t o = (size_t)(r0 + r) * D_MODEL + e;
        unsigned short hi, lo;
        split_bf16(aq[r] * scale, hi, lo); Qhi[o] = hi; Qlo[o] = lo;
        split_bf16(ak[r], hi, lo);         Khi[o] = hi; Klo[o] = lo;
        split_bf16(av[r], hi, lo);         vsh[0][r][e] = hi; vsh[1][r][e] = lo;
    }
    __syncthreads();

    // coalesced V^T store: head-row k = (s&1023)*4 + e/32, head-dim = e&31
    {
        const int b  = r0 >> 12;
        const int s0 = r0 & (SEQ - 1);
        const int h  = s0 >> 10;
        const size_t vtb = (size_t)(b * 4 + h) * (32 * SEQ);
        const int d = e >> 2;                // 0..31 head-dim
        const int j = e & 3;                 // 8-k segment
        const int kk0 = (s0 & 1023) << 2;
#pragma unroll
        for (int hl = 0; hl < 2; ++hl) {
            short8 tmp;
#pragma unroll
            for (int i = 0; i < 8; ++i) {
                const int kl = j * 8 + i;
                tmp[i] = (short)vsh[hl][kl >> 2][(kl & 3) * 32 + d];
            }
            unsigned short* dst = (hl ? Vtlo : Vthi) + vtb + (size_t)d * SEQ + kk0 + j * 8;
            *(short8*)dst = tmp;
        }
    }
}

__global__ __launch_bounds__(128) void qkv_kernel(
    const int* __restrict__ seq, const void* emb,
    const float* __restrict__ wqt, const float* __restrict__ wkt,
    const float* __restrict__ wvt,
    unsigned short* Qhi, unsigned short* Qlo,
    unsigned short* Khi, unsigned short* Klo,
    unsigned short* Vthi, unsigned short* Vtlo,
    const int* __restrict__ flag)
{
    if (*flag)
        qkv_body<float>(seq, (const float*)emb, wqt, wkt, wvt,
                        Qhi, Qlo, Khi, Klo, Vthi, Vtlo);
    else
        qkv_body<__hip_bfloat16>(seq, (const __hip_bfloat16*)emb, wqt, wkt, wvt,
                                 Qhi, Qlo, Khi, Klo, Vthi, Vtlo);
}

// ---------------------------------------------------------------------------
// Kernel 2: MFMA flash attention — UNCHANGED from R20 (verified 104us,
// absmax 0.0156). 1024-thr block = 16 waves = 4 waves/SIMD; 48 VGPR fits
// the 64-cap; wave = (rt, kh-quarter); 6 QK + 4 PV MFMAs per 32-col chunk;
// pbuf/comb LDS union; exact 4-way kh combine.
// ---------------------------------------------------------------------------
__global__ __launch_bounds__(1024, 1) void attn_kernel(
    const unsigned short* __restrict__ Qhi, const unsigned short* __restrict__ Qlo,
    const unsigned short* __restrict__ Khi, const unsigned short* __restrict__ Klo,
    const unsigned short* __restrict__ Vthi, const unsigned short* __restrict__ Vtlo,
    float* __restrict__ A)
{
    const int bh   = blockIdx.x;
    const int pair = blockIdx.y;
    const size_t baseQ  = (size_t)(bh >> 2) * SEQ * D_MODEL + (size_t)(bh & 3) * SEQ * HEAD_DIM;
    const size_t baseVt = (size_t)bh * (32 * SEQ);

    const int tid  = threadIdx.x;
    const int wid  = __builtin_amdgcn_readfirstlane(tid >> 6);
    const int lane = tid & 63;
    const int rt   = wid & 3;
    const int kh   = wid >> 2;
    const int quad = lane >> 4;
    const int col  = lane & 15;

    __shared__ float shbuf[16 * 560];
    float* pb = &shbuf[wid * 560];

#pragma unroll
    for (int ti = 0; ti < 2; ++ti) {
        const int qt = ti ? pair : (63 - pair);
        const int qrow0 = qt * 64 + rt * 16;

        short8 qhiF, qloF;
        {
            const size_t qo = baseQ + (size_t)(qrow0 + col) * HEAD_DIM + quad * 8;
            qhiF = *(const short8*)(Qhi + qo);
            qloF = *(const short8*)(Qlo + qo);
        }

        f32x4 O0 = {0.f, 0.f, 0.f, 0.f};
        f32x4 O1 = {0.f, 0.f, 0.f, 0.f};
        float m[4] = {0.f, 0.f, 0.f, 0.f};
        float l[4] = {0.f, 0.f, 0.f, 0.f};

        const int N   = 2 * (qt + 1);
        const int nb  = N >> 2, rem = N & 3;
        const int cnt  = nb + ((kh < rem) ? 1 : 0);
        const int cbeg = kh * nb + ((kh < rem) ? kh : rem);

        for (int c = cbeg; c < cbeg + cnt; ++c) {
            const int kbase = c * 32;
            const size_t k0o = baseQ + (size_t)(kbase + col) * HEAD_DIM + quad * 8;
            const size_t k1o = baseQ + (size_t)(kbase + 16 + col) * HEAD_DIM + quad * 8;
            const short8 k0h = *(const short8*)(Khi + k0o);
            const short8 k0l = *(const short8*)(Klo + k0o);
            const short8 k1h = *(const short8*)(Khi + k1o);
            const short8 k1l = *(const short8*)(Klo + k1o);

            f32x4 s0 = {0.f, 0.f, 0.f, 0.f};
            f32x4 s1 = {0.f, 0.f, 0.f, 0.f};
            s0 = __builtin_amdgcn_mfma_f32_16x16x32_bf16(qhiF, k0h, s0, 0, 0, 0);
            s0 = __builtin_amdgcn_mfma_f32_16x16x32_bf16(qhiF, k0l, s0, 0, 0, 0);
            s0 = __builtin_amdgcn_mfma_f32_16x16x32_bf16(qloF, k0h, s0, 0, 0, 0);
            s1 = __builtin_amdgcn_mfma_f32_16x16x32_bf16(qhiF, k1h, s1, 0, 0, 0);
            s1 = __builtin_amdgcn_mfma_f32_16x16x32_bf16(qhiF, k1l, s1, 0, 0, 0);
            s1 = __builtin_amdgcn_mfma_f32_16x16x32_bf16(qloF, k1h, s1, 0, 0, 0);

            float p0[4], p1[4], cm[4];
#pragma unroll
            for (int r = 0; r < 4; ++r) {
                const int rowg = qrow0 + quad * 4 + r;
                p0[r] = (kbase + col      <= rowg) ? fabsf(s0[r]) : -1.f;
                p1[r] = (kbase + 16 + col <= rowg) ? fabsf(s1[r]) : -1.f;
                cm[r] = fmaxf(p0[r], p1[r]);
            }
#pragma unroll
            for (int off = 1; off < 16; off <<= 1) {
#pragma unroll
                for (int r = 0; r < 4; ++r) cm[r] = fmaxf(cm[r], __shfl_xor(cm[r], off, 64));
            }
#pragma unroll
            for (int r = 0; r < 4; ++r) {
                const float nm = fmaxf(m[r], cm[r]);
                const float al = __expf(m[r] - nm);
                l[r] *= al; O0[r] *= al; O1[r] *= al; m[r] = nm;
            }
#pragma unroll
            for (int r = 0; r < 4; ++r) {
                const float e0 = (p0[r] >= 0.f) ? __expf(p0[r] - m[r]) : 0.f;
                const float e1 = (p1[r] >= 0.f) ? __expf(p1[r] - m[r]) : 0.f;
                l[r] += e0 + e1;
                pb[(quad * 4 + r) * 34 + col]      = e0;
                pb[(quad * 4 + r) * 34 + 16 + col] = e1;
            }
            short8 ph;
            {
                const float* pr = &pb[col * 34 + quad * 8];
#pragma unroll
                for (int j = 0; j < 8; ++j) ph[j] = (short)rne_bf16(pr[j]);
            }
            const size_t v0o = baseVt + (size_t)col * SEQ + kbase + quad * 8;
            const size_t v1o = baseVt + (size_t)(16 + col) * SEQ + kbase + quad * 8;
            const short8 v0h = *(const short8*)(Vthi + v0o);
            const short8 v0l = *(const short8*)(Vtlo + v0o);
            const short8 v1h = *(const short8*)(Vthi + v1o);
            const short8 v1l = *(const short8*)(Vtlo + v1o);

            O0 = __builtin_amdgcn_mfma_f32_16x16x32_bf16(ph, v0h, O0, 0, 0, 0);
            O0 = __builtin_amdgcn_mfma_f32_16x16x32_bf16(ph, v0l, O0, 0, 0, 0);
            O1 = __builtin_amdgcn_mfma_f32_16x16x32_bf16(ph, v1h, O1, 0, 0, 0);
            O1 = __builtin_amdgcn_mfma_f32_16x16x32_bf16(ph, v1l, O1, 0, 0, 0);
        }

#pragma unroll
        for (int off = 1; off < 16; off <<= 1) {
#pragma unroll
            for (int r = 0; r < 4; ++r) l[r] += __shfl_xor(l[r], off, 64);
        }

        __syncthreads();
        {
            float* cb = &shbuf[(rt * 4 + kh) * 560];
#pragma unroll
            for (int r = 0; r < 4; ++r) {
                const int row = quad * 4 + r;
                cb[row * 35 + col]      = O0[r];
                cb[row * 35 + 16 + col] = O1[r];
            }
            if (col == 0) {
#pragma unroll
                for (int r = 0; r < 4; ++r) {
                    cb[(quad * 4 + r) * 35 + 32] = m[r];
                    cb[(quad * 4 + r) * 35 + 33] = l[r];
                }
            }
        }
        __syncthreads();
        if (kh == 0) {
            const int row = lane >> 2;
            const int d8  = (lane & 3) * 8;
            float M = 0.f;
#pragma unroll
            for (int q = 0; q < 4; ++q)
                M = fmaxf(M, shbuf[(rt * 4 + q) * 560 + row * 35 + 32]);
            float a[4], L = 0.f;
#pragma unroll
            for (int q = 0; q < 4; ++q) {
                a[q] = __expf(shbuf[(rt * 4 + q) * 560 + row * 35 + 32] - M);
                L += a[q] * shbuf[(rt * 4 + q) * 560 + row * 35 + 33];
            }
            const float invL = 1.f / L;
            float* Ao = A + baseQ + (size_t)(qrow0 + row) * HEAD_DIM + d8;
#pragma unroll
            for (int d = 0; d < 8; ++d) {
                float o = 0.f;
#pragma unroll
                for (int q = 0; q < 4; ++q)
                    o += a[q] * shbuf[(rt * 4 + q) * 560 + row * 35 + d8 + d];
                Ao[d] = o * invL;
            }
        }
        __syncthreads();
    }
}

// ---------------------------------------------------------------------------
// Kernel 3: out = att @ Wo^T  (R21: coalesced pre-transposed wo reads)
// ---------------------------------------------------------------------------
template <typename T>
__device__ __forceinline__ void out_proj_body(
    const float* __restrict__ att, const float* __restrict__ wot, T* __restrict__ out)
{
    const int e = threadIdx.x;
    const int r0 = blockIdx.x * RROWS;
    __shared__ __align__(16) float xs[RROWS][D_MODEL];
#pragma unroll
    for (int r = 0; r < RROWS; ++r)
        xs[r][e] = att[(size_t)(r0 + r) * D_MODEL + e];
    __syncthreads();

    float acc[RROWS];
#pragma unroll
    for (int r = 0; r < RROWS; ++r) acc[r] = 0.f;
    for (int d = 0; d < D_MODEL; d += 4) {
        float4 xr[RROWS];
#pragma unroll
        for (int r = 0; r < RROWS; ++r) xr[r] = *(const float4*)&xs[r][d];
#pragma unroll
        for (int dd = 0; dd < 4; ++dd) {
            const float w_ = wot[(size_t)(d + dd) * 128 + e];   // coalesced
#pragma unroll
            for (int r = 0; r < RROWS; ++r) {
                const float x = (dd == 0) ? xr[r].x : (dd == 1) ? xr[r].y
                              : (dd == 2) ? xr[r].z : xr[r].w;
                acc[r] += x * w_;
            }
        }
    }
#pragma unroll
    for (int r = 0; r < RROWS; ++r)
        storef(out, (size_t)(r0 + r) * D_MODEL + e, acc[r]);
}

__global__ __launch_bounds__(128) void out_proj_kernel(
    const float* __restrict__ att, const float* __restrict__ wot, void* out,
    const int* __restrict__ flag)
{
    if (*flag)
        out_proj_body<float>(att, wot, (float*)out);
    else
        out_proj_body<__hip_bfloat16>(att, wot, (__hip_bfloat16*)out);
}

extern "C" void kernel_launch(void* const* d_in, const int* in_sizes, int n_in,
                              void* d_out, int out_size, void* d_ws, size_t ws_size,
                              hipStream_t stream) {
    const int* seq = (const int*)d_in[0];
    const void* emb = d_in[1];
    const void* wq  = d_in[2];
    const void* wk  = d_in[3];
    const void* wv  = d_in[4];
    const void* wo  = d_in[5];

    const size_t N = (size_t)BATCH * SEQ * D_MODEL;   // 1,048,576 elements
    int*            flag = (int*)d_ws;
    unsigned short* Qhi  = (unsigned short*)((char*)d_ws + 256);
    unsigned short* Qlo  = Qhi + N;
    unsigned short* Khi  = Qlo + N;
    unsigned short* Klo  = Khi + N;
    unsigned short* Vthi = Klo + N;
    unsigned short* Vtlo = Vthi + N;
    float*          A    = (float*)(Vtlo + N);        // fp32 attn output (4 MB)
    float*          wt   = A + N;                     // 4 x 128x128 f32 transposed

    detect_kernel<<<dim3(1), dim3(64), 0, stream>>>((const unsigned short*)wq, flag);
    wt_kernel<<<dim3(4, 64), dim3(256), 0, stream>>>(wq, wk, wv, wo, wt, flag);
    qkv_kernel<<<dim3(BATCH * SEQ / RROWS), dim3(128), 0, stream>>>(
        seq, emb, wt, wt + 16384, wt + 32768,
        Qhi, Qlo, Khi, Klo, Vthi, Vtlo, flag);
    attn_kernel<<<dim3(BATCH * NUM_HEAD, 32), dim3(1024), 0, stream>>>(
        Qhi, Qlo, Khi, Klo, Vthi, Vtlo, A);
    out_proj_kernel<<<dim3(BATCH * SEQ / RROWS), dim3(128), 0, stream>>>(
        A, wt + 49152, d_out, flag);
}